// Round 1
// baseline (91.287 us; speedup 1.0000x reference)
//
#include <hip/hip_runtime.h>

// Paged-KV index construction.
// out[b*P + p] = (p < ceil(len[b]/64)) ? req_to_token[pool[b], clip(start[b]+p*64)] >> 6 : 0
// Harness delivers all integer inputs as int32 and reads the int64 reference
// output back as int32 — so we write raw int32 values to d_out.
//
// v2: 4 pages/thread, int4 stores, wave-uniform batch index (scalar b-lookups),
//     1-wave blocks. Residual-latency optimization; the measured dur is
//     dominated by two ~42us harness poison fills (256 MiB each @ ~80% HBM peak).

#define PAGE_SHIFT 6
#define PAGE_SIZE 64

// Fast path: max_num_pages % 4 == 0 and threads_per_b (= max_num_pages/4) is a
// multiple of 64, so every 64-lane wave sees a single batch index b.
__global__ __launch_bounds__(64) void kv_indices_vec4(
    const int* __restrict__ req_to_token,
    const int* __restrict__ req_pool_indices,
    const int* __restrict__ page_kernel_lens,
    const int* __restrict__ kv_start_idx,
    int4* __restrict__ out,
    int max_ctx, int tpb_shift, int nthreads) {

    int gtid = blockIdx.x * blockDim.x + threadIdx.x;
    if (gtid >= nthreads) return;

    int b = gtid >> tpb_shift;                 // wave-uniform by construction
    int t = gtid & ((1 << tpb_shift) - 1);     // which int4 within row b
    b = __builtin_amdgcn_readfirstlane(b);     // force SGPR -> s_load broadcasts

    int kv_start  = kv_start_idx[b];
    int len       = page_kernel_lens[b];
    int row       = req_pool_indices[b];
    int num_paged = (len + PAGE_SIZE - 1) >> PAGE_SHIFT;

    const int* rowp = req_to_token + (long long)row * (long long)max_ctx;

    int p0 = t << 2;
    int d[4];
    #pragma unroll
    for (int i = 0; i < 4; ++i) {
        int off = kv_start + ((p0 + i) << PAGE_SHIFT);
        off = min(max(off, 0), max_ctx - 1);
        d[i] = rowp[off];                      // 4 independent in-flight gathers
    }

    int4 v;
    #pragma unroll
    for (int i = 0; i < 4; ++i) {
        ((int*)&v)[i] = ((p0 + i) < num_paged) ? (d[i] >> PAGE_SHIFT) : 0;
    }
    // element index: (b*max_num_pages + p0)/4 == (b<<tpb_shift) + t == gtid
    out[gtid] = v;
}

// Fallback (shape-generic) scalar path — the previously verified kernel.
__global__ void kv_indices_scalar(const int* __restrict__ req_to_token,
                                  const int* __restrict__ req_pool_indices,
                                  const int* __restrict__ page_kernel_lens,
                                  const int* __restrict__ kv_start_idx,
                                  int* __restrict__ out,
                                  int max_ctx, int max_num_pages, int total) {
    int idx = blockIdx.x * blockDim.x + threadIdx.x;
    if (idx >= total) return;
    int b = idx / max_num_pages;
    int p = idx - b * max_num_pages;

    int kv_start  = kv_start_idx[b];
    int len       = page_kernel_lens[b];
    int num_paged = (len + PAGE_SIZE - 1) >> PAGE_SHIFT;

    int off = kv_start + (p << PAGE_SHIFT);
    off = min(max(off, 0), max_ctx - 1);

    int row = req_pool_indices[b];
    int data = req_to_token[(long long)row * (long long)max_ctx + off];

    out[idx] = (p < num_paged) ? (data >> PAGE_SHIFT) : 0;
}

extern "C" void kernel_launch(void* const* d_in, const int* in_sizes, int n_in,
                              void* d_out, int out_size, void* d_ws, size_t ws_size,
                              hipStream_t stream) {
    const int* req_to_token     = (const int*)d_in[0];
    const int* req_pool_indices = (const int*)d_in[1];
    const int* page_kernel_lens = (const int*)d_in[2];
    const int* kv_start_idx     = (const int*)d_in[3];

    int batch         = in_sizes[1];                 // 256
    int max_num_pages = out_size / batch;            // 512
    int max_ctx       = max_num_pages * PAGE_SIZE;   // 32768
    int total         = out_size;                    // 131072

    // Fast path requires: P % 4 == 0 and (P/4) a power of two that is >= 64,
    // so each wave maps to exactly one batch row.
    int tpb = max_num_pages >> 2;                    // threads per batch row (128)
    bool pow2 = (max_num_pages & 3) == 0 && (tpb & (tpb - 1)) == 0 && tpb >= 64;

    if (pow2) {
        int tpb_shift = __builtin_ctz(tpb);          // 7
        int nthreads  = batch * tpb;                 // 32768
        int block = 64;                              // one wave per block
        int grid  = (nthreads + block - 1) / block;  // 512
        kv_indices_vec4<<<grid, block, 0, stream>>>(
            req_to_token, req_pool_indices, page_kernel_lens, kv_start_idx,
            (int4*)d_out, max_ctx, tpb_shift, nthreads);
    } else {
        int block = 256;
        int grid  = (total + block - 1) / block;
        kv_indices_scalar<<<grid, block, 0, stream>>>(
            req_to_token, req_pool_indices, page_kernel_lens, kv_start_idx,
            (int*)d_out, max_ctx, max_num_pages, total);
    }
}